// Round 1
// baseline (503.592 us; speedup 1.0000x reference)
//
#include <hip/hip_runtime.h>

typedef __bf16 v8bf __attribute__((ext_vector_type(8)));
typedef float  v4f  __attribute__((ext_vector_type(4)));

__device__ inline unsigned pack_bf16x2(float x, float y) {
    unsigned short a = __builtin_bit_cast(unsigned short, (__bf16)x);
    unsigned short b = __builtin_bit_cast(unsigned short, (__bf16)y);
    return (unsigned)a | ((unsigned)b << 16);
}

// ---- counters layout in ws (int indices) ----
// [0..7]  cnt1   [8..15] cnt2   [16..23] cursor1  [24..31] cursor2
// [32..40] gs1   [41..49] gs2   [50..58] tb1      [59..67] tb2

// Fused weight-pack (blocks 0..1919) + offset histogram (blocks 1920..2431).
__global__ void pack_hist(const float* __restrict__ W1, const float* __restrict__ W2,
                          const float* __restrict__ W3, const float* __restrict__ T2,
                          const float* __restrict__ T3,
                          __bf16* __restrict__ W3T, __bf16* __restrict__ BT3,
                          __bf16* __restrict__ BT2,
                          const int* __restrict__ off1, int n1,
                          const int* __restrict__ off2, int n2, int* __restrict__ ctr) {
    if (blockIdx.x < 1920) {
        int idx = blockIdx.x * 256 + threadIdx.x;
        if (idx < 32768) {
            // W3T[d][c] = W3[c][d], d<128, c<256
            int c = idx & 255, d = idx >> 8;
            W3T[d * 256 + c] = (__bf16)W3[c * 128 + d];
        } else if (idx < 32768 + 262144) {
            // BT3[k][d][c]: c<128 -> T3[k][c][d], else W2[c-128][d]
            int t = idx - 32768;
            int c = t & 255, rest = t >> 8;
            int d = rest & 127, k = rest >> 7;
            float v = (c < 128) ? T3[((k * 128 + c) * 128) + d] : W2[(c - 128) * 128 + d];
            BT3[t] = (__bf16)v;
        } else if (idx < 32768 + 262144 + 196608) {
            // BT2[k][d][c]: c<128 -> T2[k][c][d], else W1[c-128][d]  (c<192)
            int t = idx - (32768 + 262144);
            int c = t % 192, rest = t / 192;
            int d = rest & 127, k = rest >> 7;
            float v = (c < 128) ? T2[((k * 128 + c) * 128) + d] : W1[(c - 128) * 128 + d];
            BT2[t] = (__bf16)v;
        }
    } else {
        __shared__ int lh[16];
        if (threadIdx.x < 16) lh[threadIdx.x] = 0;
        __syncthreads();
        int total = n1 + n2;
        for (int idx = (blockIdx.x - 1920) * 256 + threadIdx.x; idx < total; idx += 512 * 256) {
            if (idx < n1) atomicAdd(&lh[off1[idx]], 1);
            else          atomicAdd(&lh[8 + off2[idx - n1]], 1);
        }
        __syncthreads();
        if (threadIdx.x < 16) {
            int c = lh[threadIdx.x];
            if (c) atomicAdd(&ctr[threadIdx.x], c);
        }
    }
}

// Scan: all 16 counter loads issued up-front (independent), then register-only
// prefix — the old version's interleaved load/store chain was a serial
// single-thread latency chain.
__global__ void scan_kernel(int* __restrict__ ctr) {
    if (threadIdx.x == 0 && blockIdx.x == 0) {
        int h[16];
#pragma unroll
        for (int x = 0; x < 16; ++x) h[x] = ctr[x];
        int s = 0, tb = 0;
#pragma unroll
        for (int g = 0; g < 8; ++g) {
            ctr[32 + g] = s; ctr[16 + g] = s; ctr[50 + g] = tb;
            s += h[g]; tb += (h[g] + 63) >> 6;
        }
        ctr[40] = s; ctr[58] = tb;
        s = 0; tb = 0;
#pragma unroll
        for (int g = 0; g < 8; ++g) {
            ctr[41 + g] = s; ctr[24 + g] = s; ctr[59 + g] = tb;
            s += h[8 + g]; tb += (h[8 + g] + 63) >> 6;
        }
        ctr[49] = s; ctr[67] = tb;
    }
}

__global__ void scatter_kernel(const int* __restrict__ off1, int n1, int nb1,
                               const int* __restrict__ off2, int n2,
                               int* __restrict__ ctr, int* __restrict__ perm1,
                               int* __restrict__ perm2) {
    __shared__ int lh[8], gb[8];
    const int* off; int n, base; int* cursor; int* perm;
    if ((int)blockIdx.x < nb1) {
        off = off1; n = n1; base = blockIdx.x * 1024; cursor = ctr + 16; perm = perm1;
    } else {
        off = off2; n = n2; base = (blockIdx.x - nb1) * 1024; cursor = ctr + 24; perm = perm2;
    }
    if (threadIdx.x < 8) lh[threadIdx.x] = 0;
    __syncthreads();
    for (int rr = 0; rr < 4; ++rr) {
        int i = base + rr * 256 + (int)threadIdx.x;
        int o = -1, rank = 0;
        if (i < n) { o = off[i]; rank = atomicAdd(&lh[o], 1); }
        __syncthreads();
        if (threadIdx.x < 8) {
            int c = lh[threadIdx.x];
            gb[threadIdx.x] = c ? atomicAdd(&cursor[threadIdx.x], c) : 0;
        }
        __syncthreads();
        if (o >= 0) perm[gb[o] + rank] = i;
        __syncthreads();
        if (threadIdx.x < 8) lh[threadIdx.x] = 0;
        __syncthreads();
    }
}

// Dense (non-gather) GEMM kept for level 3 (BW-bound, sequential staging).
template <int K, int CP, int CS, bool GATHER, bool OUT_BF16, int MINW>
__global__ __launch_bounds__(256, MINW) void gemm_k(
    const float* __restrict__ Askip, const __bf16* __restrict__ Aprev,
    const __bf16* __restrict__ BT, const int* __restrict__ perm,
    const int* __restrict__ parent, const int* __restrict__ ctr,
    int gs_off, int tb_off, void* __restrict__ outp, int M) {
    constexpr int LD = K + 8;
    __shared__ __align__(16) __bf16 Al[64 * LD];
    __shared__ int orow[64];

    int g, r0, mcount;
    if constexpr (GATHER) {
        const int* tb = ctr + tb_off;
        int b = blockIdx.x;
        if (b >= tb[8]) return;
        g = 0;
        while (b >= tb[g + 1]) ++g;
        const int* gs = ctr + gs_off;
        r0 = gs[g] + (b - tb[g]) * 64;
        mcount = min(64, gs[g + 1] - r0);
    } else {
        g = 0;
        r0 = blockIdx.x * 64;
        mcount = min(64, M - r0);
    }

    const int tid = threadIdx.x;
    const int lane = tid & 63;
    const int w = tid >> 6;
    const int m = lane & 15;
    const int q = lane >> 4;

    constexpr int KS = K / 32;
    v8bf bfrag[2][KS];
    {
        const __bf16* bbase = BT + ((size_t)g * 128 + w * 32 + m) * K + q * 8;
#pragma unroll
        for (int t = 0; t < 2; ++t)
#pragma unroll
            for (int kk = 0; kk < KS; ++kk)
                bfrag[t][kk] = *(const v8bf*)(bbase + (size_t)t * 16 * K + kk * 32);
    }

    {
        int j = tid >> 2, part = tid & 3;
        if (j < mcount) {
            int i, p = 0;
            if constexpr (GATHER) { i = perm[r0 + j]; p = parent[i]; }
            else { i = r0 + j; }
            if (part == 0) orow[j] = i;
            __bf16* arow = &Al[j * LD];
            if constexpr (CP > 0) {
                const uint4* src = (const uint4*)(Aprev + (size_t)p * CP) + part * (CP / 32);
                uint4* dst = (uint4*)arow + part * (CP / 32);
#pragma unroll
                for (int v = 0; v < CP / 32; ++v) dst[v] = src[v];
            }
            {
                const float4* src = (const float4*)(Askip + (size_t)i * CS) + part * (CS / 16);
                uint4* dst = (uint4*)(arow + CP + part * (CS / 4));
#pragma unroll
                for (int v = 0; v < CS / 16; v += 2) {
                    float4 f0 = src[v], f1 = src[v + 1];
                    uint4 wd;
                    wd.x = pack_bf16x2(f0.x, f0.y);
                    wd.y = pack_bf16x2(f0.z, f0.w);
                    wd.z = pack_bf16x2(f1.x, f1.y);
                    wd.w = pack_bf16x2(f1.z, f1.w);
                    dst[v / 2] = wd;
                }
            }
        }
    }
    __syncthreads();

    v4f acc[4][2] = {};
#pragma unroll
    for (int kk = 0; kk < KS; ++kk) {
#pragma unroll
        for (int rt = 0; rt < 4; ++rt) {
            v8bf a = *(const v8bf*)(&Al[(rt * 16 + m) * LD + q * 8 + kk * 32]);
            acc[rt][0] = __builtin_amdgcn_mfma_f32_16x16x32_bf16(a, bfrag[0][kk], acc[rt][0], 0, 0, 0);
            acc[rt][1] = __builtin_amdgcn_mfma_f32_16x16x32_bf16(a, bfrag[1][kk], acc[rt][1], 0, 0, 0);
        }
    }

#pragma unroll
    for (int rt = 0; rt < 4; ++rt) {
#pragma unroll
        for (int r = 0; r < 4; ++r) {
            int j = rt * 16 + q * 4 + r;
            if (j < mcount) {
                size_t row = (size_t)orow[j] * 128 + w * 32;
                if constexpr (OUT_BF16) {
                    __bf16* out = (__bf16*)outp;
                    out[row + m]      = (__bf16)acc[rt][0][r];
                    out[row + 16 + m] = (__bf16)acc[rt][1][r];
                } else {
                    float* out = (float*)outp;
                    out[row + m]      = acc[rt][0][r];
                    out[row + 16 + m] = acc[rt][1][r];
                }
            }
        }
    }
}

// Paired-tile pipelined gather-GEMM: block b owns tiles 2b and 2b+1.
//  - tb/gs tables read with unrolled independent loads + branchless select
//    (kills the 8-deep dependent pointer-chase at block start).
//  - tile1's perm/parent prefetched before tile0 stages; tile1's gathered
//    row loads are issued right after the first sync so they fly under
//    tile0's MFMA + epilogue.
//  - B fragments are reused across the pair (reloaded only if the pair
//    straddles a group boundary).
template <int K, int CP, int CS, bool OUT_BF16, bool PREF_SKIP>
__global__ __launch_bounds__(256, 3) void gemm_pair(
    const float* __restrict__ Askip, const __bf16* __restrict__ Aprev,
    const __bf16* __restrict__ BT, const int* __restrict__ perm,
    const int* __restrict__ parent, const int* __restrict__ ctr,
    int gs_off, int tb_off, void* __restrict__ outp) {
    constexpr int LD = K + 8;   // +8 bf16 pad: 4-dword bank rotation, <=2-way (free)
    constexpr int KS = K / 32;
    constexpr int NAP = CP / 32;   // uint4 per staging thread (Aprev part)
    constexpr int NSK = CS / 16;   // float4 per staging thread (skip part)
    __shared__ __align__(16) __bf16 Al[64 * LD];
    __shared__ int orow[64];

    // ---- parallel table read: all 18 loads independent, const-indexed regs ----
    int tb[9], gs[9];
#pragma unroll
    for (int x = 0; x < 9; ++x) tb[x] = ctr[tb_off + x];
#pragma unroll
    for (int x = 0; x < 9; ++x) gs[x] = ctr[gs_off + x];

    const int total = tb[8];
    const int t0 = (int)blockIdx.x * 2;
    const int t1 = t0 + 1;
    if (t0 >= total) return;
    const bool has1 = (t1 < total);

    // branchless group locate (no runtime-indexed array -> stays in VGPRs)
    auto locate = [&](int t, int& g, int& r0, int& mc) {
        int gg = 0, tbg = tb[0], gsg = gs[0], gse = gs[1];
#pragma unroll
        for (int x = 1; x < 8; ++x) {
            if (t >= tb[x]) { gg = x; tbg = tb[x]; gsg = gs[x]; gse = gs[x + 1]; }
        }
        g = gg; r0 = gsg + (t - tbg) * 64; mc = min(64, gse - r0);
    };
    int g0, r00, mc0, g1 = 0, r01 = 0, mc1 = 0;
    locate(t0, g0, r00, mc0);
    if (has1) locate(t1, g1, r01, mc1);

    const int tid = (int)threadIdx.x;
    const int lane = tid & 63;
    const int w = tid >> 6;   // wave = 32-col slice
    const int m = lane & 15;
    const int q = lane >> 4;
    const int j = tid >> 2;   // staging row
    const int part = tid & 3; // staging quarter-row

    // ---- both tiles' index chains issued up-front (chains run in parallel) ----
    int i0 = -1, p0 = 0, i1 = -1, p1 = 0;
    if (j < mc0) i0 = perm[r00 + j];
    if (has1 && j < mc1) i1 = perm[r01 + j];
    if (j < mc0) p0 = parent[i0];
    if (has1 && j < mc1) p1 = parent[i1];

    // ---- B fragments for g0 (L2-hot; overlaps index chains) ----
    v8bf bfrag[2][KS];
    {
        const __bf16* bbase = BT + ((size_t)g0 * 128 + w * 32 + m) * K + q * 8;
#pragma unroll
        for (int t = 0; t < 2; ++t)
#pragma unroll
            for (int kk = 0; kk < KS; ++kk)
                bfrag[t][kk] = *(const v8bf*)(bbase + (size_t)t * 16 * K + kk * 32);
    }

    // ---- tile0 data -> regs ----
    uint4 apr[NAP];
    float4 skr[NSK];
    if (j < mc0) {
        const uint4* asrc = (const uint4*)(Aprev + (size_t)p0 * CP) + part * NAP;
#pragma unroll
        for (int v = 0; v < NAP; ++v) apr[v] = asrc[v];
        const float4* ssrc = (const float4*)(Askip + (size_t)i0 * CS) + part * NSK;
#pragma unroll
        for (int v = 0; v < NSK; ++v) skr[v] = ssrc[v];
    }

    auto stage = [&](int mc, int i) {
        if (j < mc) {
            if (part == 0) orow[j] = i;
            __bf16* arow = &Al[j * LD];
            uint4* dst = (uint4*)arow + part * NAP;
#pragma unroll
            for (int v = 0; v < NAP; ++v) dst[v] = apr[v];
            uint4* sdst = (uint4*)(arow + CP + part * (CS / 4));
#pragma unroll
            for (int v = 0; v < NSK; v += 2) {
                uint4 wd;
                wd.x = pack_bf16x2(skr[v].x, skr[v].y);
                wd.y = pack_bf16x2(skr[v].z, skr[v].w);
                wd.z = pack_bf16x2(skr[v + 1].x, skr[v + 1].y);
                wd.w = pack_bf16x2(skr[v + 1].z, skr[v + 1].w);
                sdst[v / 2] = wd;
            }
        }
    };

    auto compute_and_store = [&](int mc) {
        v4f acc[4][2] = {};
#pragma unroll
        for (int kk = 0; kk < KS; ++kk) {
#pragma unroll
            for (int rt = 0; rt < 4; ++rt) {
                v8bf a = *(const v8bf*)(&Al[(rt * 16 + m) * LD + q * 8 + kk * 32]);
                acc[rt][0] = __builtin_amdgcn_mfma_f32_16x16x32_bf16(a, bfrag[0][kk], acc[rt][0], 0, 0, 0);
                acc[rt][1] = __builtin_amdgcn_mfma_f32_16x16x32_bf16(a, bfrag[1][kk], acc[rt][1], 0, 0, 0);
            }
        }
#pragma unroll
        for (int rt = 0; rt < 4; ++rt) {
#pragma unroll
            for (int r = 0; r < 4; ++r) {
                int jj = rt * 16 + q * 4 + r;
                if (jj < mc) {
                    size_t row = (size_t)orow[jj] * 128 + w * 32;
                    if constexpr (OUT_BF16) {
                        __bf16* out = (__bf16*)outp;
                        out[row + m]      = (__bf16)acc[rt][0][r];
                        out[row + 16 + m] = (__bf16)acc[rt][1][r];
                    } else {
                        float* out = (float*)outp;
                        out[row + m]      = acc[rt][0][r];
                        out[row + 16 + m] = acc[rt][1][r];
                    }
                }
            }
        }
    };

    // ---- stage tile0, then issue tile1's gathered loads under compute0 ----
    stage(mc0, i0);
    __syncthreads();

    if (has1 && j < mc1) {
        const uint4* asrc = (const uint4*)(Aprev + (size_t)p1 * CP) + part * NAP;
#pragma unroll
        for (int v = 0; v < NAP; ++v) apr[v] = asrc[v];
        if constexpr (PREF_SKIP) {
            const float4* ssrc = (const float4*)(Askip + (size_t)i1 * CS) + part * NSK;
#pragma unroll
            for (int v = 0; v < NSK; ++v) skr[v] = ssrc[v];
        }
    }

    compute_and_store(mc0);

    if (!has1) return;

    // skip part for tile1 (when too register-hungry to prefetch under compute):
    // issue right after epilogue0 — overlaps store drain + barrier.
    if constexpr (!PREF_SKIP) {
        if (j < mc1) {
            const float4* ssrc = (const float4*)(Askip + (size_t)i1 * CS) + part * NSK;
#pragma unroll
            for (int v = 0; v < NSK; ++v) skr[v] = ssrc[v];
        }
    }
    if (g1 != g0) {  // rare: pair straddles a group boundary
        const __bf16* bbase = BT + ((size_t)g1 * 128 + w * 32 + m) * K + q * 8;
#pragma unroll
        for (int t = 0; t < 2; ++t)
#pragma unroll
            for (int kk = 0; kk < KS; ++kk)
                bfrag[t][kk] = *(const v8bf*)(bbase + (size_t)t * 16 * K + kk * 32);
    }
    __syncthreads();  // epilogue0's orow reads done; Al free

    stage(mc1, i1);
    __syncthreads();

    compute_and_store(mc1);
}

extern "C" void kernel_launch(void* const* d_in, const int* in_sizes, int n_in,
                              void* d_out, int out_size, void* d_ws, size_t ws_size,
                              hipStream_t stream) {
    const float* feats1 = (const float*)d_in[0];
    const float* feats2 = (const float*)d_in[1];
    const float* feats3 = (const float*)d_in[2];
    const int* parent1 = (const int*)d_in[3];
    const int* offset1 = (const int*)d_in[4];
    const int* parent2 = (const int*)d_in[5];
    const int* offset2 = (const int*)d_in[6];
    const float* W1 = (const float*)d_in[7];
    const float* W2 = (const float*)d_in[8];
    const float* W3 = (const float*)d_in[9];
    const float* T2 = (const float*)d_in[10];
    const float* T3 = (const float*)d_in[11];
    const int N1 = in_sizes[0] / 64;
    const int N2 = in_sizes[1] / 128;
    const int N3 = in_sizes[2] / 256;

    char* p = (char*)d_ws;
    auto take = [&](size_t bytes) {
        char* r = p;
        p += (bytes + 255) & ~(size_t)255;
        return r;
    };
    __bf16* y3b = (__bf16*)take((size_t)N3 * 128 * 2);
    __bf16* y2b = (__bf16*)take((size_t)N2 * 128 * 2);
    __bf16* W3T = (__bf16*)take((size_t)32768 * 2);
    __bf16* BT3 = (__bf16*)take((size_t)262144 * 2);
    __bf16* BT2 = (__bf16*)take((size_t)196608 * 2);
    int* perm1 = (int*)take((size_t)N1 * 4);
    int* perm2 = (int*)take((size_t)N2 * 4);
    int* ctr = (int*)take(68 * 4);

    hipMemsetAsync(ctr, 0, 16 * 4, stream);
    pack_hist<<<2432, 256, 0, stream>>>(W1, W2, W3, T2, T3, W3T, BT3, BT2,
                                        offset1, N1, offset2, N2, ctr);
    scan_kernel<<<1, 64, 0, stream>>>(ctr);
    int nb1 = (N1 + 1023) / 1024, nb2 = (N2 + 1023) / 1024;
    scatter_kernel<<<nb1 + nb2, 256, 0, stream>>>(offset1, N1, nb1, offset2, N2, ctr, perm1,
                                                  perm2);
    // y3 = bf16(feats3 @ W3): K=256 all-skip, no gather
    gemm_k<256, 0, 256, false, true, 3><<<(N3 + 63) / 64, 256, 0, stream>>>(
        feats3, nullptr, W3T, nullptr, nullptr, nullptr, 0, 0, y3b, N3);
    // y2 = tconv(y3,T3) + feats2@W2  (grouped, K=128+128), paired-tile pipeline
    int nt2 = (N2 + 63) / 64 + 8;
    gemm_pair<256, 128, 128, true, false><<<(nt2 + 1) / 2, 256, 0, stream>>>(
        feats2, y3b, BT3, perm2, parent2, ctr, 41, 59, y2b);
    // out = tconv(y2,T2) + feats1@W1  (grouped, K=128+64), fp32 out, paired-tile
    int nt1 = (N1 + 63) / 64 + 8;
    gemm_pair<192, 128, 64, false, true><<<(nt1 + 1) / 2, 256, 0, stream>>>(
        feats1, y2b, BT2, perm1, parent1, ctr, 32, 50, d_out);
}

// Round 2
// 471.149 us; speedup vs baseline: 1.0689x; 1.0689x over previous
//
#include <hip/hip_runtime.h>

typedef __bf16 v8bf __attribute__((ext_vector_type(8)));
typedef float  v4f  __attribute__((ext_vector_type(4)));

__device__ inline unsigned pack_bf16x2(float x, float y) {
    unsigned short a = __builtin_bit_cast(unsigned short, (__bf16)x);
    unsigned short b = __builtin_bit_cast(unsigned short, (__bf16)y);
    return (unsigned)a | ((unsigned)b << 16);
}

// ---- counters layout in ws (int indices) ----
// [0..7]  cnt1   [8..15] cnt2   [16..23] cursor1  [24..31] cursor2
// [32..40] gs1   [41..49] gs2   [50..58] tb1      [59..67] tb2

// Fused weight-pack (blocks 0..1919) + offset histogram (blocks 1920..2431).
__global__ void pack_hist(const float* __restrict__ W1, const float* __restrict__ W2,
                          const float* __restrict__ W3, const float* __restrict__ T2,
                          const float* __restrict__ T3,
                          __bf16* __restrict__ W3T, __bf16* __restrict__ BT3,
                          __bf16* __restrict__ BT2,
                          const int* __restrict__ off1, int n1,
                          const int* __restrict__ off2, int n2, int* __restrict__ ctr) {
    if (blockIdx.x < 1920) {
        int idx = blockIdx.x * 256 + threadIdx.x;
        if (idx < 32768) {
            // W3T[d][c] = W3[c][d], d<128, c<256
            int c = idx & 255, d = idx >> 8;
            W3T[d * 256 + c] = (__bf16)W3[c * 128 + d];
        } else if (idx < 32768 + 262144) {
            // BT3[k][d][c]: c<128 -> T3[k][c][d], else W2[c-128][d]
            int t = idx - 32768;
            int c = t & 255, rest = t >> 8;
            int d = rest & 127, k = rest >> 7;
            float v = (c < 128) ? T3[((k * 128 + c) * 128) + d] : W2[(c - 128) * 128 + d];
            BT3[t] = (__bf16)v;
        } else if (idx < 32768 + 262144 + 196608) {
            // BT2[k][d][c]: c<128 -> T2[k][c][d], else W1[c-128][d]  (c<192)
            int t = idx - (32768 + 262144);
            int c = t % 192, rest = t / 192;
            int d = rest & 127, k = rest >> 7;
            float v = (c < 128) ? T2[((k * 128 + c) * 128) + d] : W1[(c - 128) * 128 + d];
            BT2[t] = (__bf16)v;
        }
    } else {
        __shared__ int lh[16];
        if (threadIdx.x < 16) lh[threadIdx.x] = 0;
        __syncthreads();
        int total = n1 + n2;
        for (int idx = (blockIdx.x - 1920) * 256 + threadIdx.x; idx < total; idx += 512 * 256) {
            if (idx < n1) atomicAdd(&lh[off1[idx]], 1);
            else          atomicAdd(&lh[8 + off2[idx - n1]], 1);
        }
        __syncthreads();
        if (threadIdx.x < 16) {
            int c = lh[threadIdx.x];
            if (c) atomicAdd(&ctr[threadIdx.x], c);
        }
    }
}

// Scan: all 16 counter loads issued up-front (independent), then register-only
// prefix sums.
__global__ void scan_kernel(int* __restrict__ ctr) {
    if (threadIdx.x == 0 && blockIdx.x == 0) {
        int h[16];
#pragma unroll
        for (int x = 0; x < 16; ++x) h[x] = ctr[x];
        int s = 0, tb = 0;
#pragma unroll
        for (int g = 0; g < 8; ++g) {
            ctr[32 + g] = s; ctr[16 + g] = s; ctr[50 + g] = tb;
            s += h[g]; tb += (h[g] + 63) >> 6;
        }
        ctr[40] = s; ctr[58] = tb;
        s = 0; tb = 0;
#pragma unroll
        for (int g = 0; g < 8; ++g) {
            ctr[41 + g] = s; ctr[24 + g] = s; ctr[59 + g] = tb;
            s += h[8 + g]; tb += (h[8 + g] + 63) >> 6;
        }
        ctr[49] = s; ctr[67] = tb;
    }
}

// Scatter rows into offset-groups. Also pre-gathers parent[] through the
// permutation (pperm[slot] = parent[perm[slot]]): parent[i] is read here
// COALESCED (i consecutive), so the gemm's index chain shrinks from
// perm->parent->row (3-deep, ~2.4k cyc) to {perm, pperm} || row (~1.2k cyc).
__global__ void scatter_kernel(const int* __restrict__ off1, int n1, int nb1,
                               const int* __restrict__ off2, int n2,
                               const int* __restrict__ par1, const int* __restrict__ par2,
                               int* __restrict__ ctr,
                               int* __restrict__ perm1, int* __restrict__ perm2,
                               int* __restrict__ pperm1, int* __restrict__ pperm2) {
    __shared__ int lh[8], gb[8];
    const int* off; const int* par; int n, base; int* cursor; int* perm; int* pperm;
    if ((int)blockIdx.x < nb1) {
        off = off1; par = par1; n = n1; base = blockIdx.x * 1024;
        cursor = ctr + 16; perm = perm1; pperm = pperm1;
    } else {
        off = off2; par = par2; n = n2; base = (blockIdx.x - nb1) * 1024;
        cursor = ctr + 24; perm = perm2; pperm = pperm2;
    }
    if (threadIdx.x < 8) lh[threadIdx.x] = 0;
    __syncthreads();
    for (int rr = 0; rr < 4; ++rr) {
        int i = base + rr * 256 + (int)threadIdx.x;
        int o = -1, rank = 0, pv = 0;
        if (i < n) { o = off[i]; pv = par[i]; rank = atomicAdd(&lh[o], 1); }
        __syncthreads();
        if (threadIdx.x < 8) {
            int c = lh[threadIdx.x];
            gb[threadIdx.x] = c ? atomicAdd(&cursor[threadIdx.x], c) : 0;
        }
        __syncthreads();
        if (o >= 0) { int pos = gb[o] + rank; perm[pos] = i; pperm[pos] = pv; }
        __syncthreads();
        if (threadIdx.x < 8) lh[threadIdx.x] = 0;
        __syncthreads();
    }
}

// Grouped gather-GEMM, A-only LDS; each wave owns a 32-col slice with B
// fragments register-resident (B is small & L2-hot: one global read/block).
//   out[i][0:128] = concat(Aprev[pperm[s]][0:CP], bf16(Askip[perm[s]][0:CS])) @ B_g
// BT[g][n][k] pre-transposed, n<128, k<K = CP+CS.
template <int K, int CP, int CS, bool GATHER, bool OUT_BF16, int MINW>
__global__ __launch_bounds__(256, MINW) void gemm_k(
    const float* __restrict__ Askip, const __bf16* __restrict__ Aprev,
    const __bf16* __restrict__ BT, const int* __restrict__ perm,
    const int* __restrict__ pperm, const int* __restrict__ ctr,
    int gs_off, int tb_off, void* __restrict__ outp, int M) {
    constexpr int LD = K + 8;  // +8 bf16 pad: 4-dword bank rotation, <=2-way (free)
    __shared__ __align__(16) __bf16 Al[64 * LD];
    __shared__ int orow[64];

    int g, r0, mcount;
    if constexpr (GATHER) {
        // Branchless parallel locate: 16 independent loads (no pointer chase),
        // named scalars only (no runtime-indexed arrays -> no scratch).
        const int* tb = ctr + tb_off;
        const int* gs = ctr + gs_off;
        int b = blockIdx.x;
        int t1 = tb[1], t2 = tb[2], t3 = tb[3], t4 = tb[4];
        int t5 = tb[5], t6 = tb[6], t7 = tb[7], t8 = tb[8];
        int s1 = gs[1], s2 = gs[2], s3 = gs[3], s4 = gs[4];
        int s5 = gs[5], s6 = gs[6], s7 = gs[7], s8 = gs[8];
        if (b >= t8) return;
        int tbg = 0, gsg = 0, gse = s1;
        if (b >= t1) { tbg = t1; gsg = s1; gse = s2; }
        if (b >= t2) { tbg = t2; gsg = s2; gse = s3; }
        if (b >= t3) { tbg = t3; gsg = s3; gse = s4; }
        if (b >= t4) { tbg = t4; gsg = s4; gse = s5; }
        if (b >= t5) { tbg = t5; gsg = s5; gse = s6; }
        if (b >= t6) { tbg = t6; gsg = s6; gse = s7; }
        if (b >= t7) { tbg = t7; gsg = s7; gse = s8; }
        g = (b >= t1) + (b >= t2) + (b >= t3) + (b >= t4) + (b >= t5) +
            (b >= t6) + (b >= t7);
        r0 = gsg + (b - tbg) * 64;
        mcount = min(64, gse - r0);
    } else {
        g = 0;
        r0 = blockIdx.x * 64;
        mcount = min(64, M - r0);
    }

    const int tid = threadIdx.x;
    const int lane = tid & 63;
    const int w = tid >> 6;   // wave = 32-col slice
    const int m = lane & 15;
    const int q = lane >> 4;

    // ---- issue index loads first (independent pair), then B frags under them ----
    int j = tid >> 2, part = tid & 3;
    int i = -1, p = 0;
    if (j < mcount) {
        if constexpr (GATHER) { i = perm[r0 + j]; p = pperm[r0 + j]; }
        else { i = r0 + j; }
    }

    constexpr int KS = K / 32;
    v8bf bfrag[2][KS];
    {
        const __bf16* bbase = BT + ((size_t)g * 128 + w * 32 + m) * K + q * 8;
#pragma unroll
        for (int t = 0; t < 2; ++t)
#pragma unroll
            for (int kk = 0; kk < KS; ++kk)
                bfrag[t][kk] = *(const v8bf*)(bbase + (size_t)t * 16 * K + kk * 32);
    }

    // ---- stage A (64 rows x K bf16) into LDS, 4 threads per row ----
    if (j < mcount) {
        if (part == 0) orow[j] = i;
        __bf16* arow = &Al[j * LD];
        if constexpr (CP > 0) {
            const uint4* src = (const uint4*)(Aprev + (size_t)p * CP) + part * (CP / 32);
            uint4* dst = (uint4*)arow + part * (CP / 32);
#pragma unroll
            for (int v = 0; v < CP / 32; ++v) dst[v] = src[v];
        }
        {
            const float4* src = (const float4*)(Askip + (size_t)i * CS) + part * (CS / 16);
            uint4* dst = (uint4*)(arow + CP + part * (CS / 4));
#pragma unroll
            for (int v = 0; v < CS / 16; v += 2) {
                float4 f0 = src[v], f1 = src[v + 1];
                uint4 wd;
                wd.x = pack_bf16x2(f0.x, f0.y);
                wd.y = pack_bf16x2(f0.z, f0.w);
                wd.z = pack_bf16x2(f1.x, f1.y);
                wd.w = pack_bf16x2(f1.z, f1.w);
                dst[v / 2] = wd;
            }
        }
    }
    __syncthreads();

    // ---- MFMA: all 64 rows x this wave's 32 cols ----
    v4f acc[4][2] = {};
#pragma unroll
    for (int kk = 0; kk < KS; ++kk) {
#pragma unroll
        for (int rt = 0; rt < 4; ++rt) {
            v8bf a = *(const v8bf*)(&Al[(rt * 16 + m) * LD + q * 8 + kk * 32]);
            acc[rt][0] = __builtin_amdgcn_mfma_f32_16x16x32_bf16(a, bfrag[0][kk], acc[rt][0], 0, 0, 0);
            acc[rt][1] = __builtin_amdgcn_mfma_f32_16x16x32_bf16(a, bfrag[1][kk], acc[rt][1], 0, 0, 0);
        }
    }

    // ---- epilogue: D[row=rt*16+q*4+r][col=w*32+t*16+m] ----
#pragma unroll
    for (int rt = 0; rt < 4; ++rt) {
#pragma unroll
        for (int r = 0; r < 4; ++r) {
            int jj = rt * 16 + q * 4 + r;
            if (jj < mcount) {
                size_t row = (size_t)orow[jj] * 128 + w * 32;
                if constexpr (OUT_BF16) {
                    __bf16* out = (__bf16*)outp;
                    out[row + m]      = (__bf16)acc[rt][0][r];
                    out[row + 16 + m] = (__bf16)acc[rt][1][r];
                } else {
                    float* out = (float*)outp;
                    out[row + m]      = acc[rt][0][r];
                    out[row + 16 + m] = acc[rt][1][r];
                }
            }
        }
    }
}

extern "C" void kernel_launch(void* const* d_in, const int* in_sizes, int n_in,
                              void* d_out, int out_size, void* d_ws, size_t ws_size,
                              hipStream_t stream) {
    const float* feats1 = (const float*)d_in[0];
    const float* feats2 = (const float*)d_in[1];
    const float* feats3 = (const float*)d_in[2];
    const int* parent1 = (const int*)d_in[3];
    const int* offset1 = (const int*)d_in[4];
    const int* parent2 = (const int*)d_in[5];
    const int* offset2 = (const int*)d_in[6];
    const float* W1 = (const float*)d_in[7];
    const float* W2 = (const float*)d_in[8];
    const float* W3 = (const float*)d_in[9];
    const float* T2 = (const float*)d_in[10];
    const float* T3 = (const float*)d_in[11];
    const int N1 = in_sizes[0] / 64;
    const int N2 = in_sizes[1] / 128;
    const int N3 = in_sizes[2] / 256;

    char* p = (char*)d_ws;
    auto take = [&](size_t bytes) {
        char* r = p;
        p += (bytes + 255) & ~(size_t)255;
        return r;
    };
    __bf16* y3b = (__bf16*)take((size_t)N3 * 128 * 2);
    __bf16* y2b = (__bf16*)take((size_t)N2 * 128 * 2);
    __bf16* W3T = (__bf16*)take((size_t)32768 * 2);
    __bf16* BT3 = (__bf16*)take((size_t)262144 * 2);
    __bf16* BT2 = (__bf16*)take((size_t)196608 * 2);
    int* perm1 = (int*)take((size_t)N1 * 4);
    int* perm2 = (int*)take((size_t)N2 * 4);
    int* pperm1 = (int*)take((size_t)N1 * 4);
    int* pperm2 = (int*)take((size_t)N2 * 4);
    int* ctr = (int*)take(68 * 4);

    hipMemsetAsync(ctr, 0, 16 * 4, stream);
    pack_hist<<<2432, 256, 0, stream>>>(W1, W2, W3, T2, T3, W3T, BT3, BT2,
                                        offset1, N1, offset2, N2, ctr);
    scan_kernel<<<1, 64, 0, stream>>>(ctr);
    int nb1 = (N1 + 1023) / 1024, nb2 = (N2 + 1023) / 1024;
    scatter_kernel<<<nb1 + nb2, 256, 0, stream>>>(offset1, N1, nb1, offset2, N2,
                                                  parent1, parent2, ctr,
                                                  perm1, perm2, pperm1, pperm2);
    // y3 = bf16(feats3 @ W3): K=256 all-skip, no gather
    gemm_k<256, 0, 256, false, true, 3><<<(N3 + 63) / 64, 256, 0, stream>>>(
        feats3, nullptr, W3T, nullptr, nullptr, nullptr, 0, 0, y3b, N3);
    // y2 = tconv(y3,T3) + feats2@W2  (grouped, K=128+128)
    gemm_k<256, 128, 128, true, true, 3><<<(N2 + 63) / 64 + 8, 256, 0, stream>>>(
        feats2, y3b, BT3, perm2, pperm2, ctr, 41, 59, y2b, N2);
    // out = tconv(y2,T2) + feats1@W1  (grouped, K=128+64), fp32 out
    gemm_k<192, 128, 64, true, false, 3><<<(N1 + 63) / 64 + 8, 256, 0, stream>>>(
        feats1, y2b, BT2, perm1, pperm1, ctr, 32, 50, d_out, N1);
}